// Round 1
// baseline (773.755 us; speedup 1.0000x reference)
//
#include <hip/hip_runtime.h>

// SAGE_Net: 2-layer GraphSAGE, N=100k, E=1.6M, 128->128->64, fp32.
// Strategy: CSR build (deterministic gather) + transform-before-aggregate for
// layer 2 (halves gather traffic) + fp32 register-tiled GEMMs (no fp32 MFMA
// on CDNA4; bf16 would blow the absmax threshold).

__global__ void k_count_deg(const int* __restrict__ ei, int E, int* __restrict__ deg) {
    int e = blockIdx.x * blockDim.x + threadIdx.x;
    if (e < E) atomicAdd(&deg[ei[E + e]], 1);
}

// 2-level exclusive scan: S1 scans 1024-elem tiles (256 thr x 4), S2 scans tile
// sums (<=128 tiles), S3 adds offsets + writes cursor copy + row_ptr[N]=E.
__global__ void k_scan1(const int* __restrict__ deg, int N,
                        int* __restrict__ row_ptr, int* __restrict__ bsums) {
    __shared__ int s[256];
    int t = threadIdx.x;
    int base = blockIdx.x * 1024 + t * 4;
    int e0 = (base + 0 < N) ? deg[base + 0] : 0;
    int e1 = (base + 1 < N) ? deg[base + 1] : 0;
    int e2 = (base + 2 < N) ? deg[base + 2] : 0;
    int e3 = (base + 3 < N) ? deg[base + 3] : 0;
    int ts = e0 + e1 + e2 + e3;
    s[t] = ts;
    __syncthreads();
    for (int off = 1; off < 256; off <<= 1) {
        int v = (t >= off) ? s[t - off] : 0;
        __syncthreads();
        s[t] += v;
        __syncthreads();
    }
    int excl = s[t] - ts;
    if (base + 0 < N) row_ptr[base + 0] = excl;
    if (base + 1 < N) row_ptr[base + 1] = excl + e0;
    if (base + 2 < N) row_ptr[base + 2] = excl + e0 + e1;
    if (base + 3 < N) row_ptr[base + 3] = excl + e0 + e1 + e2;
    if (t == 255) bsums[blockIdx.x] = s[255];
}

__global__ void k_scan2(int* __restrict__ bsums, int nb) {
    __shared__ int s[128];
    int t = threadIdx.x;
    int v = (t < nb) ? bsums[t] : 0;
    s[t] = v;
    __syncthreads();
    for (int off = 1; off < 128; off <<= 1) {
        int u = (t >= off) ? s[t - off] : 0;
        __syncthreads();
        s[t] += u;
        __syncthreads();
    }
    if (t < nb) bsums[t] = s[t] - v;  // exclusive
}

__global__ void k_scan3(int* __restrict__ row_ptr, int* __restrict__ cursor,
                        const int* __restrict__ bsums, int N, int E) {
    int i = blockIdx.x * blockDim.x + threadIdx.x;
    if (i < N) {
        int v = row_ptr[i] + bsums[i >> 10];
        row_ptr[i] = v;
        cursor[i] = v;
    } else if (i == N) {
        row_ptr[N] = E;
    }
}

__global__ void k_fill(const int* __restrict__ ei, int E,
                       int* __restrict__ cursor, int* __restrict__ col) {
    int e = blockIdx.x * blockDim.x + threadIdx.x;
    if (e < E) {
        int dst = ei[E + e];
        int pos = atomicAdd(&cursor[dst], 1);
        col[pos] = ei[e];  // src
    }
}

// mean-aggregate 128-dim rows of x into mean[]: one wave per node, float2/lane
__global__ void k_agg_mean128(const int* __restrict__ row_ptr, const int* __restrict__ col,
                              const float* __restrict__ x, float* __restrict__ mean, int N) {
    int node = blockIdx.x * 4 + (threadIdx.x >> 6);
    int lane = threadIdx.x & 63;
    if (node >= N) return;
    int beg = row_ptr[node], end = row_ptr[node + 1];
    float sx = 0.f, sy = 0.f;
    for (int e = beg; e < end; ++e) {
        int src = col[e];
        float2 v = *(const float2*)(x + (size_t)src * 128 + lane * 2);
        sx += v.x; sy += v.y;
    }
    float inv = 1.0f / (float)max(end - beg, 1);
    float2 o; o.x = sx * inv; o.y = sy * inv;
    *(float2*)(mean + (size_t)node * 128 + lane * 2) = o;
}

// h[i][j] = relu( sum_k mean[i][k]*W1l[j][k] + sum_k x[i][k]*W1r[j][k] + b1[j] )
// Block: 64 nodes x 128 cols, K=256 in 4 chunks of 64. 8x4 register tile.
__global__ __launch_bounds__(256) void k_gemm1(
        const float* __restrict__ mean, const float* __restrict__ x,
        const float* __restrict__ W1l, const float* __restrict__ W1r,
        const float* __restrict__ b1, float* __restrict__ h, int N) {
    __shared__ float As[64][64];    // [kk][node]
    __shared__ float Ws[64][128];   // [kk][j]
    int t = threadIdx.x;
    int node0 = blockIdx.x * 64;
    int ri = (t >> 5) * 8;
    int cj = (t & 31) * 4;
    float acc[8][4];
#pragma unroll
    for (int r = 0; r < 8; r++)
#pragma unroll
        for (int c = 0; c < 4; c++) acc[r][c] = 0.f;

    int nl = t & 63;   // node-in-tile for A staging
    int ah = t >> 6;   // 0..3 (k sub-chunk of 16)
    int jj = t & 127;  // W row for staging
    int wh = t >> 7;   // 0..1 (k sub-chunk of 32)

    for (int k0 = 0; k0 < 256; k0 += 64) {
        const float* Asrc = (k0 < 128) ? mean : x;
        const float* Wsrc = (k0 < 128) ? W1l : W1r;
        int kb = k0 & 127;
        int grow = node0 + nl;
        const float* ap = Asrc + (size_t)grow * 128 + kb + ah * 16;
#pragma unroll
        for (int c = 0; c < 16; c += 4) {
            float4 v = (grow < N) ? *(const float4*)(ap + c) : make_float4(0, 0, 0, 0);
            As[ah * 16 + c + 0][nl] = v.x;
            As[ah * 16 + c + 1][nl] = v.y;
            As[ah * 16 + c + 2][nl] = v.z;
            As[ah * 16 + c + 3][nl] = v.w;
        }
        const float* wp = Wsrc + (size_t)jj * 128 + kb + wh * 32;
#pragma unroll
        for (int c = 0; c < 32; c += 4) {
            float4 v = *(const float4*)(wp + c);
            Ws[wh * 32 + c + 0][jj] = v.x;
            Ws[wh * 32 + c + 1][jj] = v.y;
            Ws[wh * 32 + c + 2][jj] = v.z;
            Ws[wh * 32 + c + 3][jj] = v.w;
        }
        __syncthreads();
#pragma unroll 8
        for (int kk = 0; kk < 64; ++kk) {
            float4 a0 = *(const float4*)&As[kk][ri];
            float4 a1 = *(const float4*)&As[kk][ri + 4];
            float4 w = *(const float4*)&Ws[kk][cj];
            float av[8] = {a0.x, a0.y, a0.z, a0.w, a1.x, a1.y, a1.z, a1.w};
            float wv[4] = {w.x, w.y, w.z, w.w};
#pragma unroll
            for (int r = 0; r < 8; r++)
#pragma unroll
                for (int c = 0; c < 4; c++) acc[r][c] += av[r] * wv[c];
        }
        __syncthreads();
    }
    float4 bv = *(const float4*)(b1 + cj);
    float bb[4] = {bv.x, bv.y, bv.z, bv.w};
#pragma unroll
    for (int r = 0; r < 8; r++) {
        int row = node0 + ri + r;
        if (row < N) {
            float4 o;
            o.x = fmaxf(acc[r][0] + bb[0], 0.f);
            o.y = fmaxf(acc[r][1] + bb[1], 0.f);
            o.z = fmaxf(acc[r][2] + bb[2], 0.f);
            o.w = fmaxf(acc[r][3] + bb[3], 0.f);
            *(float4*)(h + (size_t)row * 128 + cj) = o;
        }
    }
}

// y2[i][j] = sum_k h[i][k] * (j<64 ? W2l[j][k] : W2r[j-64][k]) + (j<64 ? 0 : b2[j-64])
__global__ __launch_bounds__(256) void k_gemm2(
        const float* __restrict__ h,
        const float* __restrict__ W2l, const float* __restrict__ W2r,
        const float* __restrict__ b2, float* __restrict__ y2, int N) {
    __shared__ float As[64][64];
    __shared__ float Ws[64][128];
    int t = threadIdx.x;
    int node0 = blockIdx.x * 64;
    int ri = (t >> 5) * 8;
    int cj = (t & 31) * 4;
    float acc[8][4];
#pragma unroll
    for (int r = 0; r < 8; r++)
#pragma unroll
        for (int c = 0; c < 4; c++) acc[r][c] = 0.f;

    int nl = t & 63;
    int ah = t >> 6;
    int jj = t & 127;
    int wh = t >> 7;
    const float* wrow = (jj < 64) ? (W2l + (size_t)jj * 128) : (W2r + (size_t)(jj - 64) * 128);

    for (int k0 = 0; k0 < 128; k0 += 64) {
        int grow = node0 + nl;
        const float* ap = h + (size_t)grow * 128 + k0 + ah * 16;
#pragma unroll
        for (int c = 0; c < 16; c += 4) {
            float4 v = (grow < N) ? *(const float4*)(ap + c) : make_float4(0, 0, 0, 0);
            As[ah * 16 + c + 0][nl] = v.x;
            As[ah * 16 + c + 1][nl] = v.y;
            As[ah * 16 + c + 2][nl] = v.z;
            As[ah * 16 + c + 3][nl] = v.w;
        }
        const float* wp = wrow + k0 + wh * 32;
#pragma unroll
        for (int c = 0; c < 32; c += 4) {
            float4 v = *(const float4*)(wp + c);
            Ws[wh * 32 + c + 0][jj] = v.x;
            Ws[wh * 32 + c + 1][jj] = v.y;
            Ws[wh * 32 + c + 2][jj] = v.z;
            Ws[wh * 32 + c + 3][jj] = v.w;
        }
        __syncthreads();
#pragma unroll 8
        for (int kk = 0; kk < 64; ++kk) {
            float4 a0 = *(const float4*)&As[kk][ri];
            float4 a1 = *(const float4*)&As[kk][ri + 4];
            float4 w = *(const float4*)&Ws[kk][cj];
            float av[8] = {a0.x, a0.y, a0.z, a0.w, a1.x, a1.y, a1.z, a1.w};
            float wv[4] = {w.x, w.y, w.z, w.w};
#pragma unroll
            for (int r = 0; r < 8; r++)
#pragma unroll
                for (int c = 0; c < 4; c++) acc[r][c] += av[r] * wv[c];
        }
        __syncthreads();
    }
    float bb[4];
    if (cj < 64) {
        bb[0] = bb[1] = bb[2] = bb[3] = 0.f;
    } else {
        float4 bv = *(const float4*)(b2 + (cj - 64));
        bb[0] = bv.x; bb[1] = bv.y; bb[2] = bv.z; bb[3] = bv.w;
    }
#pragma unroll
    for (int r = 0; r < 8; r++) {
        int row = node0 + ri + r;
        if (row < N) {
            float4 o;
            o.x = acc[r][0] + bb[0];
            o.y = acc[r][1] + bb[1];
            o.z = acc[r][2] + bb[2];
            o.w = acc[r][3] + bb[3];
            *(float4*)(y2 + (size_t)row * 128 + cj) = o;
        }
    }
}

// out[i][j] = mean_agg(y2[:,0:64])[i][j] + y2[i][64+j]   (j<64), wave per node
__global__ void k_agg_out(const int* __restrict__ row_ptr, const int* __restrict__ col,
                          const float* __restrict__ y2, float* __restrict__ out, int N) {
    int node = blockIdx.x * 4 + (threadIdx.x >> 6);
    int lane = threadIdx.x & 63;
    if (node >= N) return;
    int beg = row_ptr[node], end = row_ptr[node + 1];
    float s = 0.f;
    for (int e = beg; e < end; ++e) {
        int src = col[e];
        s += y2[(size_t)src * 128 + lane];
    }
    float inv = 1.0f / (float)max(end - beg, 1);
    out[(size_t)node * 64 + lane] = s * inv + y2[(size_t)node * 128 + 64 + lane];
}

extern "C" void kernel_launch(void* const* d_in, const int* in_sizes, int n_in,
                              void* d_out, int out_size, void* d_ws, size_t ws_size,
                              hipStream_t stream) {
    const float* x   = (const float*)d_in[0];
    const float* W1l = (const float*)d_in[1];
    const float* W1r = (const float*)d_in[2];
    const float* b1  = (const float*)d_in[3];
    const float* W2l = (const float*)d_in[4];
    const float* W2r = (const float*)d_in[5];
    const float* b2  = (const float*)d_in[6];
    const int*   ei  = (const int*)d_in[7];
    int N = in_sizes[0] / 128;
    int E = in_sizes[7] / 2;
    float* out = (float*)d_out;

    char* w = (char*)d_ws;
    size_t off = 0;
    auto alloc = [&](size_t bytes) -> char* {
        char* p = w + off;
        off += (bytes + 255) & ~(size_t)255;
        return p;
    };
    int*   deg     = (int*)alloc((size_t)N * 4);
    int*   row_ptr = (int*)alloc((size_t)(N + 1) * 4);
    int*   cursor  = (int*)alloc((size_t)N * 4);
    int*   bsums   = (int*)alloc(512);
    int*   col     = (int*)alloc((size_t)E * 4);
    float* mean    = (float*)alloc((size_t)N * 128 * 4);
    float* h       = (float*)alloc((size_t)N * 128 * 4);
    float* y2      = mean;  // mean is dead after gemm1; reuse buffer

    hipMemsetAsync(deg, 0, (size_t)N * 4, stream);
    int eb = (E + 255) / 256;
    k_count_deg<<<eb, 256, 0, stream>>>(ei, E, deg);
    int nb1 = (N + 1023) / 1024;  // 98 for N=100000, must be <=128
    k_scan1<<<nb1, 256, 0, stream>>>(deg, N, row_ptr, bsums);
    k_scan2<<<1, 128, 0, stream>>>(bsums, nb1);
    k_scan3<<<(N + 1 + 255) / 256, 256, 0, stream>>>(row_ptr, cursor, bsums, N, E);
    k_fill<<<eb, 256, 0, stream>>>(ei, E, cursor, col);

    int ab = (N + 3) / 4;
    k_agg_mean128<<<ab, 256, 0, stream>>>(row_ptr, col, x, mean, N);
    int gb = (N + 63) / 64;
    k_gemm1<<<gb, 256, 0, stream>>>(mean, x, W1l, W1r, b1, h, N);
    k_gemm2<<<gb, 256, 0, stream>>>(h, W2l, W2r, b2, y2, N);
    k_agg_out<<<ab, 256, 0, stream>>>(row_ptr, col, y2, out, N);
}

// Round 2
// 585.011 us; speedup vs baseline: 1.3226x; 1.3226x over previous
//
#include <hip/hip_runtime.h>

// SAGE_Net: 2-layer GraphSAGE, N=100k, E=1.6M, 128->128->64, fp32.
// R2: bf16 gather copies (halve gather traffic) + 8-deep edge unroll (MLP)
// in both aggregation kernels. Accumulation stays fp32. GEMMs unchanged.

typedef unsigned int uint32;

__device__ __forceinline__ uint32 pack_bf16_rne(float a, float b) {
    uint32 ua = __float_as_uint(a);
    uint32 ub = __float_as_uint(b);
    uint32 ra = (ua + 0x7fffu + ((ua >> 16) & 1u)) >> 16;
    uint32 rb = (ub + 0x7fffu + ((ub >> 16) & 1u)) >> 16;
    return ra | (rb << 16);
}
__device__ __forceinline__ float bf_lo(uint32 v) { return __uint_as_float(v << 16); }
__device__ __forceinline__ float bf_hi(uint32 v) { return __uint_as_float(v & 0xffff0000u); }

// x [n4*4 floats] -> xb packed bf16 pairs [n4*2 uints]
__global__ void k_to_bf16(const float* __restrict__ x, uint32* __restrict__ xb, long n4) {
    long i = (long)blockIdx.x * blockDim.x + threadIdx.x;
    if (i >= n4) return;
    float4 v = ((const float4*)x)[i];
    uint2 o;
    o.x = pack_bf16_rne(v.x, v.y);
    o.y = pack_bf16_rne(v.z, v.w);
    ((uint2*)xb)[i] = o;
}

__global__ void k_count_deg(const int* __restrict__ ei, int E, int* __restrict__ deg) {
    int e = blockIdx.x * blockDim.x + threadIdx.x;
    if (e < E) atomicAdd(&deg[ei[E + e]], 1);
}

__global__ void k_scan1(const int* __restrict__ deg, int N,
                        int* __restrict__ row_ptr, int* __restrict__ bsums) {
    __shared__ int s[256];
    int t = threadIdx.x;
    int base = blockIdx.x * 1024 + t * 4;
    int e0 = (base + 0 < N) ? deg[base + 0] : 0;
    int e1 = (base + 1 < N) ? deg[base + 1] : 0;
    int e2 = (base + 2 < N) ? deg[base + 2] : 0;
    int e3 = (base + 3 < N) ? deg[base + 3] : 0;
    int ts = e0 + e1 + e2 + e3;
    s[t] = ts;
    __syncthreads();
    for (int off = 1; off < 256; off <<= 1) {
        int v = (t >= off) ? s[t - off] : 0;
        __syncthreads();
        s[t] += v;
        __syncthreads();
    }
    int excl = s[t] - ts;
    if (base + 0 < N) row_ptr[base + 0] = excl;
    if (base + 1 < N) row_ptr[base + 1] = excl + e0;
    if (base + 2 < N) row_ptr[base + 2] = excl + e0 + e1;
    if (base + 3 < N) row_ptr[base + 3] = excl + e0 + e1 + e2;
    if (t == 255) bsums[blockIdx.x] = s[255];
}

__global__ void k_scan2(int* __restrict__ bsums, int nb) {
    __shared__ int s[128];
    int t = threadIdx.x;
    int v = (t < nb) ? bsums[t] : 0;
    s[t] = v;
    __syncthreads();
    for (int off = 1; off < 128; off <<= 1) {
        int u = (t >= off) ? s[t - off] : 0;
        __syncthreads();
        s[t] += u;
        __syncthreads();
    }
    if (t < nb) bsums[t] = s[t] - v;  // exclusive
}

__global__ void k_scan3(int* __restrict__ row_ptr, int* __restrict__ cursor,
                        const int* __restrict__ bsums, int N, int E) {
    int i = blockIdx.x * blockDim.x + threadIdx.x;
    if (i < N) {
        int v = row_ptr[i] + bsums[i >> 10];
        row_ptr[i] = v;
        cursor[i] = v;
    } else if (i == N) {
        row_ptr[N] = E;
    }
}

__global__ void k_fill(const int* __restrict__ ei, int E,
                       int* __restrict__ cursor, int* __restrict__ col) {
    int e = blockIdx.x * blockDim.x + threadIdx.x;
    if (e < E) {
        int dst = ei[E + e];
        int pos = atomicAdd(&cursor[dst], 1);
        col[pos] = ei[e];  // src
    }
}

// mean-aggregate bf16 x rows (64 uints/row) -> mean fp32 [N,128]
// wave per node, lane owns elems (2*lane, 2*lane+1); 8-deep edge unroll.
__global__ void k_agg_mean(const int* __restrict__ rp, const int* __restrict__ col,
                           const uint32* __restrict__ xb, float* __restrict__ mean, int N) {
    int node = blockIdx.x * 4 + (threadIdx.x >> 6);
    int lane = threadIdx.x & 63;
    if (node >= N) return;
    int beg = rp[node], end = rp[node + 1];
    float s0 = 0.f, s1 = 0.f;
    int e = beg;
    for (; e + 8 <= end; e += 8) {
        int c0 = col[e + 0], c1 = col[e + 1], c2 = col[e + 2], c3 = col[e + 3];
        int c4 = col[e + 4], c5 = col[e + 5], c6 = col[e + 6], c7 = col[e + 7];
        uint32 v0 = xb[(size_t)c0 * 64 + lane];
        uint32 v1 = xb[(size_t)c1 * 64 + lane];
        uint32 v2 = xb[(size_t)c2 * 64 + lane];
        uint32 v3 = xb[(size_t)c3 * 64 + lane];
        uint32 v4 = xb[(size_t)c4 * 64 + lane];
        uint32 v5 = xb[(size_t)c5 * 64 + lane];
        uint32 v6 = xb[(size_t)c6 * 64 + lane];
        uint32 v7 = xb[(size_t)c7 * 64 + lane];
        s0 += bf_lo(v0) + bf_lo(v1) + bf_lo(v2) + bf_lo(v3)
            + bf_lo(v4) + bf_lo(v5) + bf_lo(v6) + bf_lo(v7);
        s1 += bf_hi(v0) + bf_hi(v1) + bf_hi(v2) + bf_hi(v3)
            + bf_hi(v4) + bf_hi(v5) + bf_hi(v6) + bf_hi(v7);
    }
    for (; e < end; ++e) {
        uint32 v = xb[(size_t)col[e] * 64 + lane];
        s0 += bf_lo(v);
        s1 += bf_hi(v);
    }
    float inv = 1.0f / (float)max(end - beg, 1);
    float2 o;
    o.x = s0 * inv;
    o.y = s1 * inv;
    *(float2*)(mean + (size_t)node * 128 + lane * 2) = o;
}

// h = relu([mean|x] @ [W1l;W1r]^T + b1), 64x128 tile, 8x4 reg tile
__global__ __launch_bounds__(256) void k_gemm1(
        const float* __restrict__ mean, const float* __restrict__ x,
        const float* __restrict__ W1l, const float* __restrict__ W1r,
        const float* __restrict__ b1, float* __restrict__ h, int N) {
    __shared__ float As[64][64];
    __shared__ float Ws[64][128];
    int t = threadIdx.x;
    int node0 = blockIdx.x * 64;
    int ri = (t >> 5) * 8;
    int cj = (t & 31) * 4;
    float acc[8][4];
#pragma unroll
    for (int r = 0; r < 8; r++)
#pragma unroll
        for (int c = 0; c < 4; c++) acc[r][c] = 0.f;

    int nl = t & 63;
    int ah = t >> 6;
    int jj = t & 127;
    int wh = t >> 7;

    for (int k0 = 0; k0 < 256; k0 += 64) {
        const float* Asrc = (k0 < 128) ? mean : x;
        const float* Wsrc = (k0 < 128) ? W1l : W1r;
        int kb = k0 & 127;
        int grow = node0 + nl;
        const float* ap = Asrc + (size_t)grow * 128 + kb + ah * 16;
#pragma unroll
        for (int c = 0; c < 16; c += 4) {
            float4 v = (grow < N) ? *(const float4*)(ap + c) : make_float4(0, 0, 0, 0);
            As[ah * 16 + c + 0][nl] = v.x;
            As[ah * 16 + c + 1][nl] = v.y;
            As[ah * 16 + c + 2][nl] = v.z;
            As[ah * 16 + c + 3][nl] = v.w;
        }
        const float* wp = Wsrc + (size_t)jj * 128 + kb + wh * 32;
#pragma unroll
        for (int c = 0; c < 32; c += 4) {
            float4 v = *(const float4*)(wp + c);
            Ws[wh * 32 + c + 0][jj] = v.x;
            Ws[wh * 32 + c + 1][jj] = v.y;
            Ws[wh * 32 + c + 2][jj] = v.z;
            Ws[wh * 32 + c + 3][jj] = v.w;
        }
        __syncthreads();
#pragma unroll 8
        for (int kk = 0; kk < 64; ++kk) {
            float4 a0 = *(const float4*)&As[kk][ri];
            float4 a1 = *(const float4*)&As[kk][ri + 4];
            float4 w = *(const float4*)&Ws[kk][cj];
            float av[8] = {a0.x, a0.y, a0.z, a0.w, a1.x, a1.y, a1.z, a1.w};
            float wv[4] = {w.x, w.y, w.z, w.w};
#pragma unroll
            for (int r = 0; r < 8; r++)
#pragma unroll
                for (int c = 0; c < 4; c++) acc[r][c] += av[r] * wv[c];
        }
        __syncthreads();
    }
    float4 bv = *(const float4*)(b1 + cj);
    float bb[4] = {bv.x, bv.y, bv.z, bv.w};
#pragma unroll
    for (int r = 0; r < 8; r++) {
        int row = node0 + ri + r;
        if (row < N) {
            float4 o;
            o.x = fmaxf(acc[r][0] + bb[0], 0.f);
            o.y = fmaxf(acc[r][1] + bb[1], 0.f);
            o.z = fmaxf(acc[r][2] + bb[2], 0.f);
            o.w = fmaxf(acc[r][3] + bb[3], 0.f);
            *(float4*)(h + (size_t)row * 128 + cj) = o;
        }
    }
}

// hl = bf16(h @ W2l^T) compact [N,64]; hr = h @ W2r^T + b2 fp32 [N,64]
__global__ __launch_bounds__(256) void k_gemm2(
        const float* __restrict__ h,
        const float* __restrict__ W2l, const float* __restrict__ W2r,
        const float* __restrict__ b2, uint32* __restrict__ hl,
        float* __restrict__ hr, int N) {
    __shared__ float As[64][64];
    __shared__ float Ws[64][128];
    int t = threadIdx.x;
    int node0 = blockIdx.x * 64;
    int ri = (t >> 5) * 8;
    int cj = (t & 31) * 4;
    float acc[8][4];
#pragma unroll
    for (int r = 0; r < 8; r++)
#pragma unroll
        for (int c = 0; c < 4; c++) acc[r][c] = 0.f;

    int nl = t & 63;
    int ah = t >> 6;
    int jj = t & 127;
    int wh = t >> 7;
    const float* wrow = (jj < 64) ? (W2l + (size_t)jj * 128) : (W2r + (size_t)(jj - 64) * 128);

    for (int k0 = 0; k0 < 128; k0 += 64) {
        int grow = node0 + nl;
        const float* ap = h + (size_t)grow * 128 + k0 + ah * 16;
#pragma unroll
        for (int c = 0; c < 16; c += 4) {
            float4 v = (grow < N) ? *(const float4*)(ap + c) : make_float4(0, 0, 0, 0);
            As[ah * 16 + c + 0][nl] = v.x;
            As[ah * 16 + c + 1][nl] = v.y;
            As[ah * 16 + c + 2][nl] = v.z;
            As[ah * 16 + c + 3][nl] = v.w;
        }
        const float* wp = wrow + k0 + wh * 32;
#pragma unroll
        for (int c = 0; c < 32; c += 4) {
            float4 v = *(const float4*)(wp + c);
            Ws[wh * 32 + c + 0][jj] = v.x;
            Ws[wh * 32 + c + 1][jj] = v.y;
            Ws[wh * 32 + c + 2][jj] = v.z;
            Ws[wh * 32 + c + 3][jj] = v.w;
        }
        __syncthreads();
#pragma unroll 8
        for (int kk = 0; kk < 64; ++kk) {
            float4 a0 = *(const float4*)&As[kk][ri];
            float4 a1 = *(const float4*)&As[kk][ri + 4];
            float4 w = *(const float4*)&Ws[kk][cj];
            float av[8] = {a0.x, a0.y, a0.z, a0.w, a1.x, a1.y, a1.z, a1.w};
            float wv[4] = {w.x, w.y, w.z, w.w};
#pragma unroll
            for (int r = 0; r < 8; r++)
#pragma unroll
                for (int c = 0; c < 4; c++) acc[r][c] += av[r] * wv[c];
        }
        __syncthreads();
    }
    if (cj < 64) {
        // left path -> bf16 compact hl (2 uints per thread-row)
#pragma unroll
        for (int r = 0; r < 8; r++) {
            int row = node0 + ri + r;
            if (row < N) {
                uint2 o;
                o.x = pack_bf16_rne(acc[r][0], acc[r][1]);
                o.y = pack_bf16_rne(acc[r][2], acc[r][3]);
                *(uint2*)(hl + (size_t)row * 32 + cj / 2) = o;
            }
        }
    } else {
        float4 bv = *(const float4*)(b2 + (cj - 64));
        float bb[4] = {bv.x, bv.y, bv.z, bv.w};
#pragma unroll
        for (int r = 0; r < 8; r++) {
            int row = node0 + ri + r;
            if (row < N) {
                float4 o;
                o.x = acc[r][0] + bb[0];
                o.y = acc[r][1] + bb[1];
                o.z = acc[r][2] + bb[2];
                o.w = acc[r][3] + bb[3];
                *(float4*)(hr + (size_t)row * 64 + (cj - 64)) = o;
            }
        }
    }
}

// out = mean_agg(hl) + hr; half-wave (32 lanes) per node, lane owns 2 elems.
__global__ void k_agg_out(const int* __restrict__ rp, const int* __restrict__ col,
                          const uint32* __restrict__ hl, const float* __restrict__ hr,
                          float* __restrict__ out, int N) {
    int node = blockIdx.x * 8 + (threadIdx.x >> 5);
    int lane = threadIdx.x & 31;
    if (node >= N) return;
    int beg = rp[node], end = rp[node + 1];
    float s0 = 0.f, s1 = 0.f;
    int e = beg;
    for (; e + 8 <= end; e += 8) {
        int c0 = col[e + 0], c1 = col[e + 1], c2 = col[e + 2], c3 = col[e + 3];
        int c4 = col[e + 4], c5 = col[e + 5], c6 = col[e + 6], c7 = col[e + 7];
        uint32 v0 = hl[(size_t)c0 * 32 + lane];
        uint32 v1 = hl[(size_t)c1 * 32 + lane];
        uint32 v2 = hl[(size_t)c2 * 32 + lane];
        uint32 v3 = hl[(size_t)c3 * 32 + lane];
        uint32 v4 = hl[(size_t)c4 * 32 + lane];
        uint32 v5 = hl[(size_t)c5 * 32 + lane];
        uint32 v6 = hl[(size_t)c6 * 32 + lane];
        uint32 v7 = hl[(size_t)c7 * 32 + lane];
        s0 += bf_lo(v0) + bf_lo(v1) + bf_lo(v2) + bf_lo(v3)
            + bf_lo(v4) + bf_lo(v5) + bf_lo(v6) + bf_lo(v7);
        s1 += bf_hi(v0) + bf_hi(v1) + bf_hi(v2) + bf_hi(v3)
            + bf_hi(v4) + bf_hi(v5) + bf_hi(v6) + bf_hi(v7);
    }
    for (; e < end; ++e) {
        uint32 v = hl[(size_t)col[e] * 32 + lane];
        s0 += bf_lo(v);
        s1 += bf_hi(v);
    }
    float inv = 1.0f / (float)max(end - beg, 1);
    float2 hv = *(const float2*)(hr + (size_t)node * 64 + lane * 2);
    float2 o;
    o.x = s0 * inv + hv.x;
    o.y = s1 * inv + hv.y;
    *(float2*)(out + (size_t)node * 64 + lane * 2) = o;
}

extern "C" void kernel_launch(void* const* d_in, const int* in_sizes, int n_in,
                              void* d_out, int out_size, void* d_ws, size_t ws_size,
                              hipStream_t stream) {
    const float* x   = (const float*)d_in[0];
    const float* W1l = (const float*)d_in[1];
    const float* W1r = (const float*)d_in[2];
    const float* b1  = (const float*)d_in[3];
    const float* W2l = (const float*)d_in[4];
    const float* W2r = (const float*)d_in[5];
    const float* b2  = (const float*)d_in[6];
    const int*   ei  = (const int*)d_in[7];
    int N = in_sizes[0] / 128;
    int E = in_sizes[7] / 2;
    float* out = (float*)d_out;

    char* w = (char*)d_ws;
    size_t off = 0;
    auto alloc = [&](size_t bytes) -> char* {
        char* p = w + off;
        off += (bytes + 255) & ~(size_t)255;
        return p;
    };
    int*    deg     = (int*)alloc((size_t)N * 4);
    int*    row_ptr = (int*)alloc((size_t)(N + 1) * 4);
    int*    cursor  = (int*)alloc((size_t)N * 4);
    int*    bsums   = (int*)alloc(512);
    int*    col     = (int*)alloc((size_t)E * 4);
    uint32* xb      = (uint32*)alloc((size_t)N * 64 * 4);       // bf16 x, 25.6 MB
    float*  mean    = (float*)alloc((size_t)N * 128 * 4);       // 51.2 MB
    float*  h       = (float*)alloc((size_t)N * 128 * 4);       // 51.2 MB
    // hl/hr alias mean (dead after gemm1): hl 12.8 MB + hr 25.6 MB <= 51.2 MB
    uint32* hl      = (uint32*)mean;
    float*  hr      = (float*)(mean + (size_t)N * 32);

    hipMemsetAsync(deg, 0, (size_t)N * 4, stream);
    long n4 = (long)N * 32;  // groups of 4 floats in x
    k_to_bf16<<<(int)((n4 + 255) / 256), 256, 0, stream>>>(x, xb, n4);
    int eb = (E + 255) / 256;
    k_count_deg<<<eb, 256, 0, stream>>>(ei, E, deg);
    int nb1 = (N + 1023) / 1024;
    k_scan1<<<nb1, 256, 0, stream>>>(deg, N, row_ptr, bsums);
    k_scan2<<<1, 128, 0, stream>>>(bsums, nb1);
    k_scan3<<<(N + 1 + 255) / 256, 256, 0, stream>>>(row_ptr, cursor, bsums, N, E);
    k_fill<<<eb, 256, 0, stream>>>(ei, E, cursor, col);

    int ab = (N + 3) / 4;
    k_agg_mean<<<ab, 256, 0, stream>>>(row_ptr, col, xb, mean, N);
    int gb = (N + 63) / 64;
    k_gemm1<<<gb, 256, 0, stream>>>(mean, x, W1l, W1r, b1, h, N);
    k_gemm2<<<gb, 256, 0, stream>>>(h, W2l, W2r, b2, hl, hr, N);
    int ob = (N + 7) / 8;
    k_agg_out<<<ob, 256, 0, stream>>>(row_ptr, col, hl, hr, out, N);
}

// Round 3
// 465.591 us; speedup vs baseline: 1.6619x; 1.2565x over previous
//
#include <hip/hip_runtime.h>

// SAGE_Net: 2-layer GraphSAGE, N=100k, E=1.6M, 128->128->64, fp32.
// R3: bucketed CSR build (kills k_fill's 16x write amplification + 1.6M
// random atomics). BK=256 nodes/bucket; edges regrouped bucket-contiguous,
// then one block per bucket emits row_ptr + col with local LDS cursors.

typedef unsigned int uint32;

__device__ __forceinline__ uint32 pack_bf16_rne(float a, float b) {
    uint32 ua = __float_as_uint(a);
    uint32 ub = __float_as_uint(b);
    uint32 ra = (ua + 0x7fffu + ((ua >> 16) & 1u)) >> 16;
    uint32 rb = (ub + 0x7fffu + ((ub >> 16) & 1u)) >> 16;
    return ra | (rb << 16);
}
__device__ __forceinline__ float bf_lo(uint32 v) { return __uint_as_float(v << 16); }
__device__ __forceinline__ float bf_hi(uint32 v) { return __uint_as_float(v & 0xffff0000u); }

__global__ void k_to_bf16(const float* __restrict__ x, uint32* __restrict__ xb, long n4) {
    long i = (long)blockIdx.x * blockDim.x + threadIdx.x;
    if (i >= n4) return;
    float4 v = ((const float4*)x)[i];
    uint2 o;
    o.x = pack_bf16_rne(v.x, v.y);
    o.y = pack_bf16_rne(v.z, v.w);
    ((uint2*)xb)[i] = o;
}

// ---- bucketed CSR build (bucket = dst >> 8, BK=256 nodes) ----

__global__ void k_bcount(const int* __restrict__ ei, int E, int NB,
                         int* __restrict__ bucket_cnt) {
    __shared__ int hist[1024];
    int t = threadIdx.x;
    for (int i = t; i < NB; i += 256) hist[i] = 0;
    __syncthreads();
    int stride = gridDim.x * 256;
    for (int e = blockIdx.x * 256 + t; e < E; e += stride)
        atomicAdd(&hist[ei[E + e] >> 8], 1);
    __syncthreads();
    for (int i = t; i < NB; i += 256) {
        int c = hist[i];
        if (c) atomicAdd(&bucket_cnt[i], c);
    }
}

// single block, 1024 threads; NB <= 1024
__global__ void k_bscan(const int* __restrict__ bucket_cnt, int NB, int E,
                        int* __restrict__ bucket_off, int* __restrict__ bucket_cur) {
    __shared__ int s[1024];
    int t = threadIdx.x;
    int v = (t < NB) ? bucket_cnt[t] : 0;
    s[t] = v;
    __syncthreads();
    for (int o = 1; o < 1024; o <<= 1) {
        int u = (t >= o) ? s[t - o] : 0;
        __syncthreads();
        s[t] += u;
        __syncthreads();
    }
    int ex = s[t] - v;
    if (t < NB) { bucket_off[t] = ex; bucket_cur[t] = ex; }
    if (t == NB - 1) bucket_off[NB] = ex + v;  // == E
}

// regroup edges into bucket-contiguous eb[]: entry = (dst&255)<<24 | src
__global__ void k_bscatter(const int* __restrict__ ei, int E, int NB,
                           int* __restrict__ bucket_cur, uint32* __restrict__ eb) {
    __shared__ int hist[1024];
    __shared__ int base[1024];
    int t = threadIdx.x;
    for (int i = t; i < NB; i += 256) hist[i] = 0;
    __syncthreads();
    int stride = gridDim.x * 256;
    for (int e = blockIdx.x * 256 + t; e < E; e += stride)
        atomicAdd(&hist[ei[E + e] >> 8], 1);
    __syncthreads();
    for (int i = t; i < NB; i += 256) {
        int c = hist[i];
        base[i] = c ? atomicAdd(&bucket_cur[i], c) : 0;
        hist[i] = 0;
    }
    __syncthreads();
    for (int e = blockIdx.x * 256 + t; e < E; e += stride) {
        int d = ei[E + e];
        int b = d >> 8;
        int r = atomicAdd(&hist[b], 1);
        eb[base[b] + r] = ((uint32)(d & 255) << 24) | (uint32)ei[e];
    }
}

// one block per bucket: degrees -> scan -> row_ptr, then cursor-fill col
__global__ void k_bfinal(const uint32* __restrict__ eb,
                         const int* __restrict__ bucket_off,
                         int* __restrict__ row_ptr, int* __restrict__ col,
                         int N, int E) {
    __shared__ int deg[256];
    __shared__ int sc[256];
    __shared__ int cur[256];
    int b = blockIdx.x;
    int t = threadIdx.x;
    int beg = bucket_off[b], end = bucket_off[b + 1];
    deg[t] = 0;
    __syncthreads();
    for (int e = beg + t; e < end; e += 256)
        atomicAdd(&deg[eb[e] >> 24], 1);
    __syncthreads();
    int v = deg[t];
    sc[t] = v;
    __syncthreads();
    for (int o = 1; o < 256; o <<= 1) {
        int u = (t >= o) ? sc[t - o] : 0;
        __syncthreads();
        sc[t] += u;
        __syncthreads();
    }
    int ex = sc[t] - v;  // exclusive node offset within bucket
    int node = b * 256 + t;
    if (node < N) row_ptr[node] = beg + ex;
    if (b == gridDim.x - 1 && t == 0) row_ptr[N] = E;
    cur[t] = ex;
    __syncthreads();
    for (int e = beg + t; e < end; e += 256) {
        uint32 u = eb[e];
        int r = atomicAdd(&cur[u >> 24], 1);
        col[beg + r] = (int)(u & 0xFFFFFFu);
    }
}

// ---- aggregation + GEMMs (unchanged from R2) ----

__global__ void k_agg_mean(const int* __restrict__ rp, const int* __restrict__ col,
                           const uint32* __restrict__ xb, float* __restrict__ mean, int N) {
    int node = blockIdx.x * 4 + (threadIdx.x >> 6);
    int lane = threadIdx.x & 63;
    if (node >= N) return;
    int beg = rp[node], end = rp[node + 1];
    float s0 = 0.f, s1 = 0.f;
    int e = beg;
    for (; e + 8 <= end; e += 8) {
        int c0 = col[e + 0], c1 = col[e + 1], c2 = col[e + 2], c3 = col[e + 3];
        int c4 = col[e + 4], c5 = col[e + 5], c6 = col[e + 6], c7 = col[e + 7];
        uint32 v0 = xb[(size_t)c0 * 64 + lane];
        uint32 v1 = xb[(size_t)c1 * 64 + lane];
        uint32 v2 = xb[(size_t)c2 * 64 + lane];
        uint32 v3 = xb[(size_t)c3 * 64 + lane];
        uint32 v4 = xb[(size_t)c4 * 64 + lane];
        uint32 v5 = xb[(size_t)c5 * 64 + lane];
        uint32 v6 = xb[(size_t)c6 * 64 + lane];
        uint32 v7 = xb[(size_t)c7 * 64 + lane];
        s0 += bf_lo(v0) + bf_lo(v1) + bf_lo(v2) + bf_lo(v3)
            + bf_lo(v4) + bf_lo(v5) + bf_lo(v6) + bf_lo(v7);
        s1 += bf_hi(v0) + bf_hi(v1) + bf_hi(v2) + bf_hi(v3)
            + bf_hi(v4) + bf_hi(v5) + bf_hi(v6) + bf_hi(v7);
    }
    for (; e < end; ++e) {
        uint32 v = xb[(size_t)col[e] * 64 + lane];
        s0 += bf_lo(v);
        s1 += bf_hi(v);
    }
    float inv = 1.0f / (float)max(end - beg, 1);
    float2 o;
    o.x = s0 * inv;
    o.y = s1 * inv;
    *(float2*)(mean + (size_t)node * 128 + lane * 2) = o;
}

__global__ __launch_bounds__(256) void k_gemm1(
        const float* __restrict__ mean, const float* __restrict__ x,
        const float* __restrict__ W1l, const float* __restrict__ W1r,
        const float* __restrict__ b1, float* __restrict__ h, int N) {
    __shared__ float As[64][64];
    __shared__ float Ws[64][128];
    int t = threadIdx.x;
    int node0 = blockIdx.x * 64;
    int ri = (t >> 5) * 8;
    int cj = (t & 31) * 4;
    float acc[8][4];
#pragma unroll
    for (int r = 0; r < 8; r++)
#pragma unroll
        for (int c = 0; c < 4; c++) acc[r][c] = 0.f;

    int nl = t & 63;
    int ah = t >> 6;
    int jj = t & 127;
    int wh = t >> 7;

    for (int k0 = 0; k0 < 256; k0 += 64) {
        const float* Asrc = (k0 < 128) ? mean : x;
        const float* Wsrc = (k0 < 128) ? W1l : W1r;
        int kb = k0 & 127;
        int grow = node0 + nl;
        const float* ap = Asrc + (size_t)grow * 128 + kb + ah * 16;
#pragma unroll
        for (int c = 0; c < 16; c += 4) {
            float4 v = (grow < N) ? *(const float4*)(ap + c) : make_float4(0, 0, 0, 0);
            As[ah * 16 + c + 0][nl] = v.x;
            As[ah * 16 + c + 1][nl] = v.y;
            As[ah * 16 + c + 2][nl] = v.z;
            As[ah * 16 + c + 3][nl] = v.w;
        }
        const float* wp = Wsrc + (size_t)jj * 128 + kb + wh * 32;
#pragma unroll
        for (int c = 0; c < 32; c += 4) {
            float4 v = *(const float4*)(wp + c);
            Ws[wh * 32 + c + 0][jj] = v.x;
            Ws[wh * 32 + c + 1][jj] = v.y;
            Ws[wh * 32 + c + 2][jj] = v.z;
            Ws[wh * 32 + c + 3][jj] = v.w;
        }
        __syncthreads();
#pragma unroll 8
        for (int kk = 0; kk < 64; ++kk) {
            float4 a0 = *(const float4*)&As[kk][ri];
            float4 a1 = *(const float4*)&As[kk][ri + 4];
            float4 w = *(const float4*)&Ws[kk][cj];
            float av[8] = {a0.x, a0.y, a0.z, a0.w, a1.x, a1.y, a1.z, a1.w};
            float wv[4] = {w.x, w.y, w.z, w.w};
#pragma unroll
            for (int r = 0; r < 8; r++)
#pragma unroll
                for (int c = 0; c < 4; c++) acc[r][c] += av[r] * wv[c];
        }
        __syncthreads();
    }
    float4 bv = *(const float4*)(b1 + cj);
    float bb[4] = {bv.x, bv.y, bv.z, bv.w};
#pragma unroll
    for (int r = 0; r < 8; r++) {
        int row = node0 + ri + r;
        if (row < N) {
            float4 o;
            o.x = fmaxf(acc[r][0] + bb[0], 0.f);
            o.y = fmaxf(acc[r][1] + bb[1], 0.f);
            o.z = fmaxf(acc[r][2] + bb[2], 0.f);
            o.w = fmaxf(acc[r][3] + bb[3], 0.f);
            *(float4*)(h + (size_t)row * 128 + cj) = o;
        }
    }
}

__global__ __launch_bounds__(256) void k_gemm2(
        const float* __restrict__ h,
        const float* __restrict__ W2l, const float* __restrict__ W2r,
        const float* __restrict__ b2, uint32* __restrict__ hl,
        float* __restrict__ hr, int N) {
    __shared__ float As[64][64];
    __shared__ float Ws[64][128];
    int t = threadIdx.x;
    int node0 = blockIdx.x * 64;
    int ri = (t >> 5) * 8;
    int cj = (t & 31) * 4;
    float acc[8][4];
#pragma unroll
    for (int r = 0; r < 8; r++)
#pragma unroll
        for (int c = 0; c < 4; c++) acc[r][c] = 0.f;

    int nl = t & 63;
    int ah = t >> 6;
    int jj = t & 127;
    int wh = t >> 7;
    const float* wrow = (jj < 64) ? (W2l + (size_t)jj * 128) : (W2r + (size_t)(jj - 64) * 128);

    for (int k0 = 0; k0 < 128; k0 += 64) {
        int grow = node0 + nl;
        const float* ap = h + (size_t)grow * 128 + k0 + ah * 16;
#pragma unroll
        for (int c = 0; c < 16; c += 4) {
            float4 v = (grow < N) ? *(const float4*)(ap + c) : make_float4(0, 0, 0, 0);
            As[ah * 16 + c + 0][nl] = v.x;
            As[ah * 16 + c + 1][nl] = v.y;
            As[ah * 16 + c + 2][nl] = v.z;
            As[ah * 16 + c + 3][nl] = v.w;
        }
        const float* wp = wrow + k0 + wh * 32;
#pragma unroll
        for (int c = 0; c < 32; c += 4) {
            float4 v = *(const float4*)(wp + c);
            Ws[wh * 32 + c + 0][jj] = v.x;
            Ws[wh * 32 + c + 1][jj] = v.y;
            Ws[wh * 32 + c + 2][jj] = v.z;
            Ws[wh * 32 + c + 3][jj] = v.w;
        }
        __syncthreads();
#pragma unroll 8
        for (int kk = 0; kk < 64; ++kk) {
            float4 a0 = *(const float4*)&As[kk][ri];
            float4 a1 = *(const float4*)&As[kk][ri + 4];
            float4 w = *(const float4*)&Ws[kk][cj];
            float av[8] = {a0.x, a0.y, a0.z, a0.w, a1.x, a1.y, a1.z, a1.w};
            float wv[4] = {w.x, w.y, w.z, w.w};
#pragma unroll
            for (int r = 0; r < 8; r++)
#pragma unroll
                for (int c = 0; c < 4; c++) acc[r][c] += av[r] * wv[c];
        }
        __syncthreads();
    }
    if (cj < 64) {
#pragma unroll
        for (int r = 0; r < 8; r++) {
            int row = node0 + ri + r;
            if (row < N) {
                uint2 o;
                o.x = pack_bf16_rne(acc[r][0], acc[r][1]);
                o.y = pack_bf16_rne(acc[r][2], acc[r][3]);
                *(uint2*)(hl + (size_t)row * 32 + cj / 2) = o;
            }
        }
    } else {
        float4 bv = *(const float4*)(b2 + (cj - 64));
        float bb[4] = {bv.x, bv.y, bv.z, bv.w};
#pragma unroll
        for (int r = 0; r < 8; r++) {
            int row = node0 + ri + r;
            if (row < N) {
                float4 o;
                o.x = acc[r][0] + bb[0];
                o.y = acc[r][1] + bb[1];
                o.z = acc[r][2] + bb[2];
                o.w = acc[r][3] + bb[3];
                *(float4*)(hr + (size_t)row * 64 + (cj - 64)) = o;
            }
        }
    }
}

__global__ void k_agg_out(const int* __restrict__ rp, const int* __restrict__ col,
                          const uint32* __restrict__ hl, const float* __restrict__ hr,
                          float* __restrict__ out, int N) {
    int node = blockIdx.x * 8 + (threadIdx.x >> 5);
    int lane = threadIdx.x & 31;
    if (node >= N) return;
    int beg = rp[node], end = rp[node + 1];
    float s0 = 0.f, s1 = 0.f;
    int e = beg;
    for (; e + 8 <= end; e += 8) {
        int c0 = col[e + 0], c1 = col[e + 1], c2 = col[e + 2], c3 = col[e + 3];
        int c4 = col[e + 4], c5 = col[e + 5], c6 = col[e + 6], c7 = col[e + 7];
        uint32 v0 = hl[(size_t)c0 * 32 + lane];
        uint32 v1 = hl[(size_t)c1 * 32 + lane];
        uint32 v2 = hl[(size_t)c2 * 32 + lane];
        uint32 v3 = hl[(size_t)c3 * 32 + lane];
        uint32 v4 = hl[(size_t)c4 * 32 + lane];
        uint32 v5 = hl[(size_t)c5 * 32 + lane];
        uint32 v6 = hl[(size_t)c6 * 32 + lane];
        uint32 v7 = hl[(size_t)c7 * 32 + lane];
        s0 += bf_lo(v0) + bf_lo(v1) + bf_lo(v2) + bf_lo(v3)
            + bf_lo(v4) + bf_lo(v5) + bf_lo(v6) + bf_lo(v7);
        s1 += bf_hi(v0) + bf_hi(v1) + bf_hi(v2) + bf_hi(v3)
            + bf_hi(v4) + bf_hi(v5) + bf_hi(v6) + bf_hi(v7);
    }
    for (; e < end; ++e) {
        uint32 v = hl[(size_t)col[e] * 32 + lane];
        s0 += bf_lo(v);
        s1 += bf_hi(v);
    }
    float inv = 1.0f / (float)max(end - beg, 1);
    float2 hv = *(const float2*)(hr + (size_t)node * 64 + lane * 2);
    float2 o;
    o.x = s0 * inv + hv.x;
    o.y = s1 * inv + hv.y;
    *(float2*)(out + (size_t)node * 64 + lane * 2) = o;
}

extern "C" void kernel_launch(void* const* d_in, const int* in_sizes, int n_in,
                              void* d_out, int out_size, void* d_ws, size_t ws_size,
                              hipStream_t stream) {
    const float* x   = (const float*)d_in[0];
    const float* W1l = (const float*)d_in[1];
    const float* W1r = (const float*)d_in[2];
    const float* b1  = (const float*)d_in[3];
    const float* W2l = (const float*)d_in[4];
    const float* W2r = (const float*)d_in[5];
    const float* b2  = (const float*)d_in[6];
    const int*   ei  = (const int*)d_in[7];
    int N = in_sizes[0] / 128;
    int E = in_sizes[7] / 2;
    int NB = (N + 255) >> 8;  // 391 for N=100000; must be <= 1024
    float* out = (float*)d_out;

    char* w = (char*)d_ws;
    size_t off = 0;
    auto alloc = [&](size_t bytes) -> char* {
        char* p = w + off;
        off += (bytes + 255) & ~(size_t)255;
        return p;
    };
    int*    row_ptr  = (int*)alloc((size_t)(N + 1) * 4);
    int*    bcnt     = (int*)alloc((size_t)(NB + 1) * 4);
    int*    boff     = (int*)alloc((size_t)(NB + 1) * 4);
    int*    bcur     = (int*)alloc((size_t)(NB + 1) * 4);
    int*    col      = (int*)alloc((size_t)E * 4);
    uint32* xb       = (uint32*)alloc((size_t)N * 64 * 4);   // bf16 x, 25.6 MB
    float*  mean     = (float*)alloc((size_t)N * 128 * 4);   // 51.2 MB
    float*  h        = (float*)alloc((size_t)N * 128 * 4);   // 51.2 MB
    uint32* eb       = (uint32*)h;   // dead before gemm1 writes h
    uint32* hl       = (uint32*)mean;  // mean dead after gemm1
    float*  hr       = (float*)(mean + (size_t)N * 32);

    hipMemsetAsync(bcnt, 0, (size_t)NB * 4, stream);
    long n4 = (long)N * 32;
    k_to_bf16<<<(int)((n4 + 255) / 256), 256, 0, stream>>>(x, xb, n4);
    k_bcount<<<256, 256, 0, stream>>>(ei, E, NB, bcnt);
    k_bscan<<<1, 1024, 0, stream>>>(bcnt, NB, E, boff, bcur);
    k_bscatter<<<128, 256, 0, stream>>>(ei, E, NB, bcur, eb);
    k_bfinal<<<NB, 256, 0, stream>>>(eb, boff, row_ptr, col, N, E);

    int ab = (N + 3) / 4;
    k_agg_mean<<<ab, 256, 0, stream>>>(row_ptr, col, xb, mean, N);
    int gb = (N + 63) / 64;
    k_gemm1<<<gb, 256, 0, stream>>>(mean, x, W1l, W1r, b1, h, N);
    k_gemm2<<<gb, 256, 0, stream>>>(h, W2l, W2r, b2, hl, hr, N);
    int ob = (N + 7) / 8;
    k_agg_out<<<ob, 256, 0, stream>>>(row_ptr, col, hl, hr, out, N);
}

// Round 4
// 421.143 us; speedup vs baseline: 1.8373x; 1.1055x over previous
//
#include <hip/hip_runtime.h>

// SAGE_Net: 2-layer GraphSAGE, N=100k, E=1.6M, 128->128->64, fp32.
// R4: GEMMs -> bf16 MFMA (32x32x16) with split-precision (hi+lo bf16,
// 3-term C = Ah.Bh + Al.Bh + Ah.Bl) so accuracy stays fp32-level.
// Weights pre-split once; activations split during LDS staging.

typedef unsigned int uint32;
typedef short bf16x4 __attribute__((ext_vector_type(4)));
typedef short bf16x8 __attribute__((ext_vector_type(8)));
typedef float f32x16 __attribute__((ext_vector_type(16)));

__device__ __forceinline__ uint32 pack_bf16_rne(float a, float b) {
    uint32 ua = __float_as_uint(a);
    uint32 ub = __float_as_uint(b);
    uint32 ra = (ua + 0x7fffu + ((ua >> 16) & 1u)) >> 16;
    uint32 rb = (ub + 0x7fffu + ((ub >> 16) & 1u)) >> 16;
    return ra | (rb << 16);
}
__device__ __forceinline__ float bf_lo(uint32 v) { return __uint_as_float(v << 16); }
__device__ __forceinline__ float bf_hi(uint32 v) { return __uint_as_float(v & 0xffff0000u); }

__device__ __forceinline__ short rne16(float v, float* back) {
    uint32 u = __float_as_uint(v);
    uint32 r = (u + 0x7fffu + ((u >> 16) & 1u)) >> 16;
    *back = __uint_as_float(r << 16);
    return (short)r;
}

__device__ __forceinline__ bf16x8 ld8(const short* p) {
    bf16x4 a = *(const bf16x4*)p;
    bf16x4 b = *(const bf16x4*)(p + 4);
    return __builtin_shufflevector(a, b, 0, 1, 2, 3, 4, 5, 6, 7);
}

__global__ void k_to_bf16(const float* __restrict__ x, uint32* __restrict__ xb, long n4) {
    long i = (long)blockIdx.x * blockDim.x + threadIdx.x;
    if (i >= n4) return;
    float4 v = ((const float4*)x)[i];
    uint2 o;
    o.x = pack_bf16_rne(v.x, v.y);
    o.y = pack_bf16_rne(v.z, v.w);
    ((uint2*)xb)[i] = o;
}

// split weights into hi/lo bf16 combined layouts:
// W1h/W1lo [128][256] (k<128 -> W1l, else W1r);  W2h/W2lo [128][128] (j<64 -> W2l, else W2r)
__global__ void k_wprep(const float* __restrict__ W1l, const float* __restrict__ W1r,
                        const float* __restrict__ W2l, const float* __restrict__ W2r,
                        short* __restrict__ W1h, short* __restrict__ W1lo,
                        short* __restrict__ W2h, short* __restrict__ W2lo) {
    int i = blockIdx.x * blockDim.x + threadIdx.x;
    float v, back;
    if (i < 32768) {
        int j = i >> 8, k = i & 255;
        v = (k < 128) ? W1l[j * 128 + k] : W1r[j * 128 + k - 128];
        float hb;
        short hs = rne16(v, &hb);
        short ls = rne16(v - hb, &back);
        W1h[i] = hs;
        W1lo[i] = ls;
    } else if (i < 32768 + 16384) {
        int i2 = i - 32768;
        int j = i2 >> 7, k = i2 & 127;
        v = (j < 64) ? W2l[j * 128 + k] : W2r[(j - 64) * 128 + k];
        float hb;
        short hs = rne16(v, &hb);
        short ls = rne16(v - hb, &back);
        W2h[i2] = hs;
        W2lo[i2] = ls;
    }
}

// ---- bucketed CSR build (bucket = dst >> 8, BK=256 nodes) ----

__global__ void k_bcount(const int* __restrict__ ei, int E, int NB,
                         int* __restrict__ bucket_cnt) {
    __shared__ int hist[1024];
    int t = threadIdx.x;
    for (int i = t; i < NB; i += 256) hist[i] = 0;
    __syncthreads();
    int stride = gridDim.x * 256;
    for (int e = blockIdx.x * 256 + t; e < E; e += stride)
        atomicAdd(&hist[ei[E + e] >> 8], 1);
    __syncthreads();
    for (int i = t; i < NB; i += 256) {
        int c = hist[i];
        if (c) atomicAdd(&bucket_cnt[i], c);
    }
}

__global__ void k_bscan(const int* __restrict__ bucket_cnt, int NB, int E,
                        int* __restrict__ bucket_off, int* __restrict__ bucket_cur) {
    __shared__ int s[1024];
    int t = threadIdx.x;
    int v = (t < NB) ? bucket_cnt[t] : 0;
    s[t] = v;
    __syncthreads();
    for (int o = 1; o < 1024; o <<= 1) {
        int u = (t >= o) ? s[t - o] : 0;
        __syncthreads();
        s[t] += u;
        __syncthreads();
    }
    int ex = s[t] - v;
    if (t < NB) { bucket_off[t] = ex; bucket_cur[t] = ex; }
    if (t == NB - 1) bucket_off[NB] = ex + v;
}

__global__ void k_bscatter(const int* __restrict__ ei, int E, int NB,
                           int* __restrict__ bucket_cur, uint32* __restrict__ eb) {
    __shared__ int hist[1024];
    __shared__ int base[1024];
    int t = threadIdx.x;
    for (int i = t; i < NB; i += 256) hist[i] = 0;
    __syncthreads();
    int stride = gridDim.x * 256;
    for (int e = blockIdx.x * 256 + t; e < E; e += stride)
        atomicAdd(&hist[ei[E + e] >> 8], 1);
    __syncthreads();
    for (int i = t; i < NB; i += 256) {
        int c = hist[i];
        base[i] = c ? atomicAdd(&bucket_cur[i], c) : 0;
        hist[i] = 0;
    }
    __syncthreads();
    for (int e = blockIdx.x * 256 + t; e < E; e += stride) {
        int d = ei[E + e];
        int b = d >> 8;
        int r = atomicAdd(&hist[b], 1);
        eb[base[b] + r] = ((uint32)(d & 255) << 24) | (uint32)ei[e];
    }
}

__global__ void k_bfinal(const uint32* __restrict__ eb,
                         const int* __restrict__ bucket_off,
                         int* __restrict__ row_ptr, int* __restrict__ col,
                         int N, int E) {
    __shared__ int deg[256];
    __shared__ int sc[256];
    __shared__ int cur[256];
    int b = blockIdx.x;
    int t = threadIdx.x;
    int beg = bucket_off[b], end = bucket_off[b + 1];
    deg[t] = 0;
    __syncthreads();
    for (int e = beg + t; e < end; e += 256)
        atomicAdd(&deg[eb[e] >> 24], 1);
    __syncthreads();
    int v = deg[t];
    sc[t] = v;
    __syncthreads();
    for (int o = 1; o < 256; o <<= 1) {
        int u = (t >= o) ? sc[t - o] : 0;
        __syncthreads();
        sc[t] += u;
        __syncthreads();
    }
    int ex = sc[t] - v;
    int node = b * 256 + t;
    if (node < N) row_ptr[node] = beg + ex;
    if (b == gridDim.x - 1 && t == 0) row_ptr[N] = E;
    cur[t] = ex;
    __syncthreads();
    for (int e = beg + t; e < end; e += 256) {
        uint32 u = eb[e];
        int r = atomicAdd(&cur[u >> 24], 1);
        col[beg + r] = (int)(u & 0xFFFFFFu);
    }
}

// ---- aggregation (unchanged from R3) ----

__global__ void k_agg_mean(const int* __restrict__ rp, const int* __restrict__ col,
                           const uint32* __restrict__ xb, float* __restrict__ mean, int N) {
    int node = blockIdx.x * 4 + (threadIdx.x >> 6);
    int lane = threadIdx.x & 63;
    if (node >= N) return;
    int beg = rp[node], end = rp[node + 1];
    float s0 = 0.f, s1 = 0.f;
    int e = beg;
    for (; e + 8 <= end; e += 8) {
        int c0 = col[e + 0], c1 = col[e + 1], c2 = col[e + 2], c3 = col[e + 3];
        int c4 = col[e + 4], c5 = col[e + 5], c6 = col[e + 6], c7 = col[e + 7];
        uint32 v0 = xb[(size_t)c0 * 64 + lane];
        uint32 v1 = xb[(size_t)c1 * 64 + lane];
        uint32 v2 = xb[(size_t)c2 * 64 + lane];
        uint32 v3 = xb[(size_t)c3 * 64 + lane];
        uint32 v4 = xb[(size_t)c4 * 64 + lane];
        uint32 v5 = xb[(size_t)c5 * 64 + lane];
        uint32 v6 = xb[(size_t)c6 * 64 + lane];
        uint32 v7 = xb[(size_t)c7 * 64 + lane];
        s0 += bf_lo(v0) + bf_lo(v1) + bf_lo(v2) + bf_lo(v3)
            + bf_lo(v4) + bf_lo(v5) + bf_lo(v6) + bf_lo(v7);
        s1 += bf_hi(v0) + bf_hi(v1) + bf_hi(v2) + bf_hi(v3)
            + bf_hi(v4) + bf_hi(v5) + bf_hi(v6) + bf_hi(v7);
    }
    for (; e < end; ++e) {
        uint32 v = xb[(size_t)col[e] * 64 + lane];
        s0 += bf_lo(v);
        s1 += bf_hi(v);
    }
    float inv = 1.0f / (float)max(end - beg, 1);
    float2 o;
    o.x = s0 * inv;
    o.y = s1 * inv;
    *(float2*)(mean + (size_t)node * 128 + lane * 2) = o;
}

// ---- MFMA GEMMs: 128x128 block tile, 4 waves x (32 rows x 4 n-tiles) ----
// LDS: Ah/Al/Bh/Bl [128][36] bf16, KC=32.

#define LDK 36

__global__ __launch_bounds__(256) void k_mgemm1(
        const float* __restrict__ mean, const float* __restrict__ x,
        const short* __restrict__ W1h, const short* __restrict__ W1lo,
        const float* __restrict__ b1, float* __restrict__ hout, int N) {
    __shared__ short Ah[128][LDK], Al[128][LDK], Bh[128][LDK], Bl[128][LDK];
    int t = threadIdx.x;
    int w = t >> 6, lane = t & 63;
    int m = lane & 31, hh = lane >> 5;
    int node0 = blockIdx.x * 128;
    f32x16 acc[4];
#pragma unroll
    for (int i = 0; i < 4; i++)
#pragma unroll
        for (int r = 0; r < 16; r++) acc[i][r] = 0.f;

    for (int seg = 0; seg < 2; seg++) {
        const float* Aseg = seg ? x : mean;
        for (int c = 0; c < 4; c++) {
            int kb = c * 32;
            // stage A (fp32 -> hi/lo bf16)
#pragma unroll
            for (int i = 0; i < 4; i++) {
                int idx = t + 256 * i;
                int r = idx >> 3, c4 = idx & 7;
                int grow = node0 + r;
                float4 v = (grow < N) ? *(const float4*)(Aseg + (size_t)grow * 128 + kb + c4 * 4)
                                      : make_float4(0, 0, 0, 0);
                float back;
                bf16x4 hi4, lo4;
                hi4[0] = rne16(v.x, &back); lo4[0] = rne16(v.x - back, &back);
                hi4[1] = rne16(v.y, &back); lo4[1] = rne16(v.y - back, &back);
                hi4[2] = rne16(v.z, &back); lo4[2] = rne16(v.z - back, &back);
                hi4[3] = rne16(v.w, &back); lo4[3] = rne16(v.w - back, &back);
                *(bf16x4*)&Ah[r][c4 * 4] = hi4;
                *(bf16x4*)&Al[r][c4 * 4] = lo4;
            }
            // stage B (pre-split bf16 copy)
#pragma unroll
            for (int i = 0; i < 4; i++) {
                int idx = t + 256 * i;
                int r = idx >> 3, c4 = idx & 7;
                int koff = seg * 128 + kb + c4 * 4;
                *(bf16x4*)&Bh[r][c4 * 4] = *(const bf16x4*)(W1h + r * 256 + koff);
                *(bf16x4*)&Bl[r][c4 * 4] = *(const bf16x4*)(W1lo + r * 256 + koff);
            }
            __syncthreads();
#pragma unroll
            for (int ks = 0; ks < 32; ks += 16) {
                int k = ks + hh * 8;
                bf16x8 af = ld8(&Ah[32 * w + m][k]);
                bf16x8 al = ld8(&Al[32 * w + m][k]);
#pragma unroll
                for (int tt = 0; tt < 4; tt++) {
                    bf16x8 bh = ld8(&Bh[32 * tt + m][k]);
                    acc[tt] = __builtin_amdgcn_mfma_f32_32x32x16_bf16(af, bh, acc[tt], 0, 0, 0);
                    acc[tt] = __builtin_amdgcn_mfma_f32_32x32x16_bf16(al, bh, acc[tt], 0, 0, 0);
                    bf16x8 bl = ld8(&Bl[32 * tt + m][k]);
                    acc[tt] = __builtin_amdgcn_mfma_f32_32x32x16_bf16(af, bl, acc[tt], 0, 0, 0);
                }
            }
            __syncthreads();
        }
    }
    // epilogue: h = relu(acc + b1)
#pragma unroll
    for (int tt = 0; tt < 4; tt++) {
        int colj = 32 * tt + m;
        float bias = b1[colj];
#pragma unroll
        for (int r = 0; r < 16; r++) {
            int row = 32 * w + (r & 3) + 8 * (r >> 2) + 4 * hh;
            int grow = node0 + row;
            if (grow < N)
                hout[(size_t)grow * 128 + colj] = fmaxf(acc[tt][r] + bias, 0.f);
        }
    }
}

__global__ __launch_bounds__(256) void k_mgemm2(
        const float* __restrict__ hin,
        const short* __restrict__ W2h, const short* __restrict__ W2lo,
        const float* __restrict__ b2, unsigned short* __restrict__ hl16,
        float* __restrict__ hr, int N) {
    __shared__ short Ah[128][LDK], Al[128][LDK], Bh[128][LDK], Bl[128][LDK];
    int t = threadIdx.x;
    int w = t >> 6, lane = t & 63;
    int m = lane & 31, hh = lane >> 5;
    int node0 = blockIdx.x * 128;
    f32x16 acc[4];
#pragma unroll
    for (int i = 0; i < 4; i++)
#pragma unroll
        for (int r = 0; r < 16; r++) acc[i][r] = 0.f;

    for (int c = 0; c < 4; c++) {
        int kb = c * 32;
#pragma unroll
        for (int i = 0; i < 4; i++) {
            int idx = t + 256 * i;
            int r = idx >> 3, c4 = idx & 7;
            int grow = node0 + r;
            float4 v = (grow < N) ? *(const float4*)(hin + (size_t)grow * 128 + kb + c4 * 4)
                                  : make_float4(0, 0, 0, 0);
            float back;
            bf16x4 hi4, lo4;
            hi4[0] = rne16(v.x, &back); lo4[0] = rne16(v.x - back, &back);
            hi4[1] = rne16(v.y, &back); lo4[1] = rne16(v.y - back, &back);
            hi4[2] = rne16(v.z, &back); lo4[2] = rne16(v.z - back, &back);
            hi4[3] = rne16(v.w, &back); lo4[3] = rne16(v.w - back, &back);
            *(bf16x4*)&Ah[r][c4 * 4] = hi4;
            *(bf16x4*)&Al[r][c4 * 4] = lo4;
        }
#pragma unroll
        for (int i = 0; i < 4; i++) {
            int idx = t + 256 * i;
            int r = idx >> 3, c4 = idx & 7;
            int koff = kb + c4 * 4;
            *(bf16x4*)&Bh[r][c4 * 4] = *(const bf16x4*)(W2h + r * 128 + koff);
            *(bf16x4*)&Bl[r][c4 * 4] = *(const bf16x4*)(W2lo + r * 128 + koff);
        }
        __syncthreads();
#pragma unroll
        for (int ks = 0; ks < 32; ks += 16) {
            int k = ks + hh * 8;
            bf16x8 af = ld8(&Ah[32 * w + m][k]);
            bf16x8 al = ld8(&Al[32 * w + m][k]);
#pragma unroll
            for (int tt = 0; tt < 4; tt++) {
                bf16x8 bh = ld8(&Bh[32 * tt + m][k]);
                acc[tt] = __builtin_amdgcn_mfma_f32_32x32x16_bf16(af, bh, acc[tt], 0, 0, 0);
                acc[tt] = __builtin_amdgcn_mfma_f32_32x32x16_bf16(al, bh, acc[tt], 0, 0, 0);
                bf16x8 bl = ld8(&Bl[32 * tt + m][k]);
                acc[tt] = __builtin_amdgcn_mfma_f32_32x32x16_bf16(af, bl, acc[tt], 0, 0, 0);
            }
        }
        __syncthreads();
    }
    // epilogue: tiles 0,1 -> hl (bf16); tiles 2,3 -> hr (fp32 + b2)
#pragma unroll
    for (int tt = 0; tt < 2; tt++) {
        int colj = 32 * tt + m;
#pragma unroll
        for (int r = 0; r < 16; r++) {
            int row = 32 * w + (r & 3) + 8 * (r >> 2) + 4 * hh;
            int grow = node0 + row;
            if (grow < N) {
                uint32 u = __float_as_uint(acc[tt][r]);
                unsigned short bits = (unsigned short)((u + 0x7fffu + ((u >> 16) & 1u)) >> 16);
                hl16[(size_t)grow * 64 + colj] = bits;
            }
        }
    }
#pragma unroll
    for (int tt = 2; tt < 4; tt++) {
        int colj = 32 * (tt - 2) + m;
        float bias = b2[colj];
#pragma unroll
        for (int r = 0; r < 16; r++) {
            int row = 32 * w + (r & 3) + 8 * (r >> 2) + 4 * hh;
            int grow = node0 + row;
            if (grow < N)
                hr[(size_t)grow * 64 + colj] = acc[tt][r] + bias;
        }
    }
}

__global__ void k_agg_out(const int* __restrict__ rp, const int* __restrict__ col,
                          const uint32* __restrict__ hl, const float* __restrict__ hr,
                          float* __restrict__ out, int N) {
    int node = blockIdx.x * 8 + (threadIdx.x >> 5);
    int lane = threadIdx.x & 31;
    if (node >= N) return;
    int beg = rp[node], end = rp[node + 1];
    float s0 = 0.f, s1 = 0.f;
    int e = beg;
    for (; e + 8 <= end; e += 8) {
        int c0 = col[e + 0], c1 = col[e + 1], c2 = col[e + 2], c3 = col[e + 3];
        int c4 = col[e + 4], c5 = col[e + 5], c6 = col[e + 6], c7 = col[e + 7];
        uint32 v0 = hl[(size_t)c0 * 32 + lane];
        uint32 v1 = hl[(size_t)c1 * 32 + lane];
        uint32 v2 = hl[(size_t)c2 * 32 + lane];
        uint32 v3 = hl[(size_t)c3 * 32 + lane];
        uint32 v4 = hl[(size_t)c4 * 32 + lane];
        uint32 v5 = hl[(size_t)c5 * 32 + lane];
        uint32 v6 = hl[(size_t)c6 * 32 + lane];
        uint32 v7 = hl[(size_t)c7 * 32 + lane];
        s0 += bf_lo(v0) + bf_lo(v1) + bf_lo(v2) + bf_lo(v3)
            + bf_lo(v4) + bf_lo(v5) + bf_lo(v6) + bf_lo(v7);
        s1 += bf_hi(v0) + bf_hi(v1) + bf_hi(v2) + bf_hi(v3)
            + bf_hi(v4) + bf_hi(v5) + bf_hi(v6) + bf_hi(v7);
    }
    for (; e < end; ++e) {
        uint32 v = hl[(size_t)col[e] * 32 + lane];
        s0 += bf_lo(v);
        s1 += bf_hi(v);
    }
    float inv = 1.0f / (float)max(end - beg, 1);
    float2 hv = *(const float2*)(hr + (size_t)node * 64 + lane * 2);
    float2 o;
    o.x = s0 * inv + hv.x;
    o.y = s1 * inv + hv.y;
    *(float2*)(out + (size_t)node * 64 + lane * 2) = o;
}

extern "C" void kernel_launch(void* const* d_in, const int* in_sizes, int n_in,
                              void* d_out, int out_size, void* d_ws, size_t ws_size,
                              hipStream_t stream) {
    const float* x   = (const float*)d_in[0];
    const float* W1l = (const float*)d_in[1];
    const float* W1r = (const float*)d_in[2];
    const float* b1  = (const float*)d_in[3];
    const float* W2l = (const float*)d_in[4];
    const float* W2r = (const float*)d_in[5];
    const float* b2  = (const float*)d_in[6];
    const int*   ei  = (const int*)d_in[7];
    int N = in_sizes[0] / 128;
    int E = in_sizes[7] / 2;
    int NB = (N + 255) >> 8;
    float* out = (float*)d_out;

    char* w = (char*)d_ws;
    size_t off = 0;
    auto alloc = [&](size_t bytes) -> char* {
        char* p = w + off;
        off += (bytes + 255) & ~(size_t)255;
        return p;
    };
    int*    row_ptr = (int*)alloc((size_t)(N + 1) * 4);
    int*    bcnt    = (int*)alloc((size_t)(NB + 1) * 4);
    int*    boff    = (int*)alloc((size_t)(NB + 1) * 4);
    int*    bcur    = (int*)alloc((size_t)(NB + 1) * 4);
    short*  W1h     = (short*)alloc(32768 * 2);
    short*  W1lo    = (short*)alloc(32768 * 2);
    short*  W2h     = (short*)alloc(16384 * 2);
    short*  W2lo    = (short*)alloc(16384 * 2);
    int*    col     = (int*)alloc((size_t)E * 4);
    uint32* xb      = (uint32*)alloc((size_t)N * 64 * 4);   // bf16 x, 25.6 MB
    float*  mean    = (float*)alloc((size_t)N * 128 * 4);   // 51.2 MB
    float*  h       = (float*)alloc((size_t)N * 128 * 4);   // 51.2 MB
    uint32* eb      = (uint32*)h;                  // dead before mgemm1 writes h
    unsigned short* hl16 = (unsigned short*)mean;  // mean dead after mgemm1
    float*  hr      = (float*)(mean + (size_t)N * 32);

    hipMemsetAsync(bcnt, 0, (size_t)NB * 4, stream);
    long n4 = (long)N * 32;
    k_to_bf16<<<(int)((n4 + 255) / 256), 256, 0, stream>>>(x, xb, n4);
    k_wprep<<<192, 256, 0, stream>>>(W1l, W1r, W2l, W2r, W1h, W1lo, W2h, W2lo);
    k_bcount<<<256, 256, 0, stream>>>(ei, E, NB, bcnt);
    k_bscan<<<1, 1024, 0, stream>>>(bcnt, NB, E, boff, bcur);
    k_bscatter<<<128, 256, 0, stream>>>(ei, E, NB, bcur, eb);
    k_bfinal<<<NB, 256, 0, stream>>>(eb, boff, row_ptr, col, N, E);

    int ab = (N + 3) / 4;
    k_agg_mean<<<ab, 256, 0, stream>>>(row_ptr, col, xb, mean, N);
    int gb = (N + 127) / 128;
    k_mgemm1<<<gb, 256, 0, stream>>>(mean, x, W1h, W1lo, b1, h, N);
    k_mgemm2<<<gb, 256, 0, stream>>>(h, W2h, W2lo, b2, hl16, hr, N);
    int ob = (N + 7) / 8;
    k_agg_out<<<ob, 256, 0, stream>>>(row_ptr, col, (const uint32*)hl16, hr, out, N);
}